// Round 10
// baseline (32945.837 us; speedup 1.0000x reference)
//
#include <hip/hip_runtime.h>

#define NROWS 65536
#define DD 256
#define KK 1024
#define NCB 8
#define QN 16777216
#define IDXN 524288

#define ROWS 64          // rows per block
#define CH 8             // d per W-chunk
#define NCHUNK (DD/CH)   // 32
#define WRL 9            // W_s row length in dwords (odd => full bank coverage)

// Defeat -ffp-contract=fast where a separately-rounded product is required.
__device__ __forceinline__ float fp32_barrier(float x) {
    asm volatile("" : "+v"(x));
    return x;
}

// ---- numpy pairwise ||w||^2 per codeword (bitwise np.sum semantics) ----
__global__ void wss_kernel(const float* __restrict__ cb, float* __restrict__ wss) {
    const int g = blockIdx.x * blockDim.x + threadIdx.x;
    if (g >= NCB * KK) return;
    const float* w = cb + (size_t)g * DD;
    float res0 = 0.f, res1 = 0.f;
    #pragma unroll
    for (int half = 0; half < 2; ++half) {
        const float* p = w + half * 128;
        float acc[8];
        #pragma unroll
        for (int j = 0; j < 8; ++j) acc[j] = fp32_barrier(p[j] * p[j]);
        #pragma unroll
        for (int i = 8; i < 128; i += 8)
            #pragma unroll
            for (int j = 0; j < 8; ++j) acc[j] += fp32_barrier(p[i + j] * p[i + j]);
        const float t = ((acc[0] + acc[1]) + (acc[2] + acc[3])) +
                        ((acc[4] + acc[5]) + (acc[6] + acc[7]));
        if (half == 0) res0 = t; else res1 = t;
    }
    wss[g] = res0 + res1;
}

// ---- one RVQ step: 16x8 register tile per lane (acc in AGPRs via unified
// file), W double-buffered through LDS in 8-d chunks, loads issued before
// compute (latency hidden), one barrier per chunk.
// Bitwise-identical arithmetic to R3-R9: each (row,k) accumulator is one fp32
// fma chain over d=0..255 ascending (accumulator persists across d-chunks);
// score = (rss - 2*a) + wss with numpy-pairwise rss/wss; first-min argmin.
__launch_bounds__(512, 1)
__global__ void step_kernel(const float* __restrict__ z, const float* __restrict__ cb,
                            float* __restrict__ out_idx, const float* __restrict__ wss,
                            double* __restrict__ loss, int c)
{
    __shared__ float r_s[ROWS][260];           // 66.6 KB
    __shared__ float W_s[2][KK * WRL];         // 2 x 36.9 KB double buffer
    __shared__ float rss_s[ROWS];
    __shared__ unsigned long long arena[ROWS][2];
    __shared__ double lred[8];

    const int tid = threadIdx.x;
    const int lane = tid & 63;
    const int wv = tid >> 6;
    const int rowbase = (wv & 3) * 16;         // this wave's 16 rows
    const int khalf = wv >> 2;                 // this wave's 512-k half
    const int row0 = blockIdx.x * ROWS;
    const size_t cK = (size_t)c * KK;
    const float* Wc = cb + cK * DD;

    // ---- stage residual tile: fp32 reference trajectory (elementwise subs) ----
    {
        const int row = tid >> 3;              // 0..63
        const int d0 = (tid & 7) * 32;         // 8 chunks of 32 d
        const int n = row0 + row;
        float rr[32];
        const float* zr = z + (size_t)n * DD + d0;
        #pragma unroll
        for (int q = 0; q < 8; ++q) {
            const float4 v = *(const float4*)(zr + q * 4);
            rr[q * 4 + 0] = v.x; rr[q * 4 + 1] = v.y;
            rr[q * 4 + 2] = v.z; rr[q * 4 + 3] = v.w;
        }
        for (int h = 0; h < c; ++h) {
            const int ih = (int)out_idx[(size_t)n * NCB + h];
            const float* w = cb + ((size_t)h * KK + ih) * DD + d0;
            #pragma unroll
            for (int q = 0; q < 8; ++q) {
                const float4 v = *(const float4*)(w + q * 4);
                rr[q * 4 + 0] -= v.x; rr[q * 4 + 1] -= v.y;
                rr[q * 4 + 2] -= v.z; rr[q * 4 + 3] -= v.w;
            }
        }
        double ssq = 0.0;
        #pragma unroll
        for (int q = 0; q < 8; ++q) {
            *(float4*)&r_s[row][d0 + q * 4] =
                make_float4(rr[q*4], rr[q*4+1], rr[q*4+2], rr[q*4+3]);
            #pragma unroll
            for (int j = 0; j < 4; ++j) {
                const double v = (double)rr[q * 4 + j];
                ssq += v * v;
            }
        }
        if (c > 0) {
            for (int off = 32; off; off >>= 1) ssq += __shfl_down(ssq, off);
            if (lane == 0) lred[wv] = ssq;
        }
    }
    __syncthreads();
    if (c > 0 && tid == 0) {
        double s = 0.0;
        #pragma unroll
        for (int w = 0; w < 8; ++w) s += lred[w];
        atomicAdd(&loss[c - 1], s);
    }

    // ---- rss: numpy pairwise (pw128 + pw128), one row per lane of wave 0 ----
    // (rss_s consumed only after the k-loop; barriers in the loop cover it)
    if (tid < 64) {
        float res[2];
        #pragma unroll
        for (int half = 0; half < 2; ++half) {
            const int base = half * 128;
            float acc[8];
            #pragma unroll
            for (int j = 0; j < 8; ++j) {
                const float x = r_s[tid][base + j];
                acc[j] = fp32_barrier(x * x);
            }
            #pragma unroll
            for (int i = 8; i < 128; i += 8)
                #pragma unroll
                for (int j = 0; j < 8; ++j) {
                    const float x = r_s[tid][base + i + j];
                    acc[j] += fp32_barrier(x * x);
                }
            res[half] = ((acc[0] + acc[1]) + (acc[2] + acc[3])) +
                        ((acc[4] + acc[5]) + (acc[6] + acc[7]));
        }
        rss_s[tid] = res[0] + res[1];
    }

    float acc[16][8];
    #pragma unroll
    for (int rr = 0; rr < 16; ++rr)
        #pragma unroll
        for (int j = 0; j < 8; ++j) acc[rr][j] = 0.f;

    const int kbase_lane = (khalf * 512 + lane) * WRL;   // dwords into a W buffer

    // ---- prologue: stage chunk 0 into buffer 0 ----
    {
        #pragma unroll
        for (int q = 0; q < 4; ++q) {
            const int f = tid + 512 * q;          // 2048 float4 pieces
            const int k = f >> 1, half = f & 1;   // 2 float4 per k-row
            const float4 v = *(const float4*)(Wc + (size_t)k * DD + half * 4);
            float* dst = &W_s[0][k * WRL + half * 4];
            dst[0] = v.x; dst[1] = v.y; dst[2] = v.z; dst[3] = v.w;
        }
    }
    __syncthreads();

    #pragma unroll 1
    for (int ch = 0; ch < NCHUNK; ++ch) {
        // issue next chunk's global loads now; latency hides under compute
        float4 pre[4];
        const bool more = (ch + 1 < NCHUNK);
        if (more) {
            const float* src = Wc + (ch + 1) * CH;
            #pragma unroll
            for (int q = 0; q < 4; ++q) {
                const int f = tid + 512 * q;
                const int k = f >> 1, half = f & 1;
                pre[q] = *(const float4*)(src + (size_t)k * DD + half * 4);
            }
        }

        const float* Wb = W_s[ch & 1];
        const int dbase = ch * CH;
        #pragma unroll
        for (int w2 = 0; w2 < CH / 2; ++w2) {
            const int dl = w2 * 2;
            float2 wv2[8];
            #pragma unroll
            for (int j = 0; j < 8; ++j)
                wv2[j] = *(const float2*)&Wb[kbase_lane + j * 64 * WRL + dl];
            #pragma unroll
            for (int rr = 0; rr < 16; ++rr) {
                const float2 rv = *(const float2*)&r_s[rowbase + rr][dbase + dl];
                #pragma unroll
                for (int j = 0; j < 8; ++j) {
                    float a = acc[rr][j];
                    a = __builtin_fmaf(rv.x, wv2[j].x, a);
                    a = __builtin_fmaf(rv.y, wv2[j].y, a);
                    acc[rr][j] = a;
                }
            }
        }

        // write next chunk into the other buffer (no one reads it this iter)
        if (more) {
            float* Wn = W_s[(ch + 1) & 1];
            #pragma unroll
            for (int q = 0; q < 4; ++q) {
                const int f = tid + 512 * q;
                const int k = f >> 1, half = f & 1;
                float* dst = &Wn[k * WRL + half * 4];
                dst[0] = pre[q].x; dst[1] = pre[q].y; dst[2] = pre[q].z; dst[3] = pre[q].w;
            }
        }
        __syncthreads();
    }

    // ---- scores + first-min argmin (wss loaded only now) ----
    float wssv[8];
    #pragma unroll
    for (int j = 0; j < 8; ++j) wssv[j] = wss[cK + khalf * 512 + j * 64 + lane];

    #pragma unroll
    for (int rr = 0; rr < 16; ++rr) {
        const float rs = rss_s[rowbase + rr];
        unsigned long long best = 0xFFFFFFFFFFFFFFFFULL;
        #pragma unroll
        for (int j = 0; j < 8; ++j) {
            const int kk = khalf * 512 + j * 64 + lane;
            const float sc = (rs - 2.0f * acc[rr][j]) + wssv[j];
            unsigned u = __float_as_uint(sc);
            u = ((int)u < 0) ? ~u : (u | 0x80000000u);
            const unsigned long long e = ((unsigned long long)u << 32) | (unsigned)kk;
            if (e < best) best = e;
        }
        #pragma unroll
        for (int off = 1; off < 64; off <<= 1) {
            const unsigned long long o = __shfl_xor(best, off);
            if (o < best) best = o;
        }
        if (lane == 0) arena[rowbase + rr][khalf] = best;
    }
    __syncthreads();
    if (tid < ROWS) {
        unsigned long long m = arena[tid][0];
        if (arena[tid][1] < m) m = arena[tid][1];
        out_idx[(size_t)(row0 + tid) * NCB + c] = (float)(int)(m & 0xFFFFFFFFULL);
    }
}

// ---- quantized (fp32 sequential accumulation, reference order) + last loss ----
__launch_bounds__(1024)
__global__ void final_kernel(const float* __restrict__ z, const float* __restrict__ cb,
                             const float* __restrict__ out_idx, float* __restrict__ outq,
                             double* __restrict__ lpart)
{
    __shared__ double lred[16];
    const int lane = threadIdx.x & 63;
    const int w = threadIdx.x >> 6;            // 0..15
    const int n = blockIdx.x * 16 + w;
    const int d = lane * 4;

    int idx[NCB];
    #pragma unroll
    for (int j = 0; j < NCB; ++j) idx[j] = (int)out_idx[(size_t)n * NCB + j];
    float4 wv[NCB];
    #pragma unroll
    for (int j = 0; j < NCB; ++j)
        wv[j] = *(const float4*)(cb + ((size_t)j * KK + idx[j]) * DD + d);

    float4 rv = *(const float4*)(z + (size_t)n * DD + d);
    float q0 = 0.f, q1 = 0.f, q2 = 0.f, q3 = 0.f;
    #pragma unroll
    for (int j = 0; j < NCB; ++j) {
        q0 += wv[j].x; q1 += wv[j].y; q2 += wv[j].z; q3 += wv[j].w;
        rv.x -= wv[j].x; rv.y -= wv[j].y; rv.z -= wv[j].z; rv.w -= wv[j].w;
    }
    *(float4*)(outq + (size_t)n * DD + d) = make_float4(q0, q1, q2, q3);

    double ss = (double)rv.x * rv.x + (double)rv.y * rv.y +
                (double)rv.z * rv.z + (double)rv.w * rv.w;
    for (int off = 32; off; off >>= 1) ss += __shfl_down(ss, off);
    if (lane == 0) lred[w] = ss;
    __syncthreads();
    if (threadIdx.x == 0) {
        double s = 0.0;
        #pragma unroll
        for (int i = 0; i < 16; ++i) s += lred[i];
        atomicAdd(&lpart[blockIdx.x & 63], s);
    }
}

__global__ void loss_write_kernel(const double* __restrict__ loss,
                                  const double* __restrict__ lpart,
                                  float* __restrict__ out_loss) {
    double s = 0.0;
    for (int i = 0; i < NCB; ++i) s += loss[i];
    for (int i = 0; i < 64; ++i) s += lpart[i];
    *out_loss = (float)(s / 16777216.0);
}

extern "C" void kernel_launch(void* const* d_in, const int* in_sizes, int n_in,
                              void* d_out, int out_size, void* d_ws, size_t ws_size,
                              hipStream_t stream)
{
    const float* z  = (const float*)d_in[0];
    const float* cb = (const float*)d_in[1];
    float* outq     = (float*)d_out;
    float* out_idx  = outq + QN;
    float* out_loss = outq + QN + IDXN;

    double* loss  = (double*)d_ws;                 // 64 B  (slots 0..6 used)
    double* lpart = (double*)((char*)d_ws + 64);   // 512 B (striped term 7)
    float*  wss   = (float*)((char*)d_ws + 1024);  // 32 KB

    hipMemsetAsync(d_ws, 0, 576, stream);
    wss_kernel<<<dim3((NCB * KK + 255) / 256), dim3(256), 0, stream>>>(cb, wss);
    for (int c = 0; c < NCB; ++c) {
        step_kernel<<<dim3(NROWS / ROWS), dim3(512), 0, stream>>>(z, cb, out_idx, wss, loss, c);
    }
    final_kernel<<<dim3(NROWS / 16), dim3(1024), 0, stream>>>(z, cb, out_idx, outq, lpart);
    loss_write_kernel<<<1, 1, 0, stream>>>(loss, lpart, out_loss);
}

// Round 11
// 4593.676 us; speedup vs baseline: 7.1720x; 7.1720x over previous
//
#include <hip/hip_runtime.h>

#define NROWS 65536
#define DD 256
#define KK 1024
#define NCB 8
#define QN 16777216
#define IDXN 524288

#define ROWS 64          // rows per block
#define CH 8             // d per W-chunk
#define NCHUNK (DD/CH)   // 32

// Defeat -ffp-contract=fast where a separately-rounded product is required.
__device__ __forceinline__ float fp32_barrier(float x) {
    asm volatile("" : "+v"(x));
    return x;
}

typedef const __attribute__((address_space(1))) void* gas_ptr;
typedef __attribute__((address_space(3))) void* las_ptr;
__device__ __forceinline__ void gll16(const float* g, float* l) {
    __builtin_amdgcn_global_load_lds((gas_ptr)g, (las_ptr)l, 16, 0, 0);
}

// ---- numpy pairwise ||w||^2 per codeword (bitwise np.sum semantics) ----
__global__ void wss_kernel(const float* __restrict__ cb, float* __restrict__ wss) {
    const int g = blockIdx.x * blockDim.x + threadIdx.x;
    if (g >= NCB * KK) return;
    const float* w = cb + (size_t)g * DD;
    float res0 = 0.f, res1 = 0.f;
    #pragma unroll
    for (int half = 0; half < 2; ++half) {
        const float* p = w + half * 128;
        float acc[8];
        #pragma unroll
        for (int j = 0; j < 8; ++j) acc[j] = fp32_barrier(p[j] * p[j]);
        #pragma unroll
        for (int i = 8; i < 128; i += 8)
            #pragma unroll
            for (int j = 0; j < 8; ++j) acc[j] += fp32_barrier(p[i + j] * p[i + j]);
        const float t = ((acc[0] + acc[1]) + (acc[2] + acc[3])) +
                        ((acc[4] + acc[5]) + (acc[6] + acc[7]));
        if (half == 0) res0 = t; else res1 = t;
    }
    wss[g] = res0 + res1;
}

// ---- transpose codebooks: W[c][k][d] -> WT[c][d][k] (one-time, 8 MB) ----
__global__ void wt_kernel(const float* __restrict__ cb, float* __restrict__ WT) {
    __shared__ float tile[64][65];
    const int b = blockIdx.x;
    const int dt = b & 3, kt = (b >> 2) & 15, cc = b >> 6;
    const int t = threadIdx.x;
    const float* src = cb + ((size_t)cc * KK + kt * 64) * DD + dt * 64;
    #pragma unroll
    for (int q = 0; q < 4; ++q) {
        const int kl = (t >> 4) + q * 16;
        const int d4 = t & 15;
        const float4 v = *(const float4*)(src + (size_t)kl * DD + d4 * 4);
        tile[d4 * 4 + 0][kl] = v.x; tile[d4 * 4 + 1][kl] = v.y;
        tile[d4 * 4 + 2][kl] = v.z; tile[d4 * 4 + 3][kl] = v.w;
    }
    __syncthreads();
    float* dst = WT + ((size_t)cc * DD + dt * 64) * KK + kt * 64;
    #pragma unroll
    for (int q = 0; q < 4; ++q) {
        const int dl = (t >> 4) + q * 16;
        const int k4 = t & 15;
        *(float4*)(dst + (size_t)dl * KK + k4 * 4) =
            make_float4(tile[dl][k4 * 4 + 0], tile[dl][k4 * 4 + 1],
                        tile[dl][k4 * 4 + 2], tile[dl][k4 * 4 + 3]);
    }
}

// ================= GLL path: W double-buffered via global_load_lds =========
// Bitwise-identical arithmetic to R3-R10: each (row,k) accumulator is one fp32
// fma chain over d=0..255 ascending; score = (rss - 2*a) + wss with numpy-
// pairwise rss/wss; first-min argmin. W_s is d-major [dl][k]: stride-1 lane
// reads (conflict-free), linear GLL destination, chunk = 32 KB contiguous WT.
__launch_bounds__(512, 1)
__global__ void step_kernel_t(const float* __restrict__ z, const float* __restrict__ cb,
                              const float* __restrict__ WT,
                              float* __restrict__ out_idx, const float* __restrict__ wss,
                              double* __restrict__ loss, int c)
{
    __shared__ float r_s[ROWS][260];           // 66.6 KB
    __shared__ float W_s[2][CH * KK];          // 2 x 32 KB double buffer
    __shared__ float rss_s[ROWS];
    __shared__ unsigned long long arena[ROWS][2];
    __shared__ double lred[8];

    const int tid = threadIdx.x;
    const int lane = tid & 63;
    const int wv = tid >> 6;
    const int rowbase = (wv & 3) * 16;         // this wave's 16 rows
    const int khalf = wv >> 2;                 // this wave's 512-k half
    const int row0 = blockIdx.x * ROWS;
    const size_t cK = (size_t)c * KK;
    const float* WTc = WT + cK * DD;           // [d][k] slice for codebook c

    // ---- stage residual tile: fp32 reference trajectory (elementwise subs) ----
    {
        const int row = tid >> 3;              // 0..63
        const int d0 = (tid & 7) * 32;         // 8 chunks of 32 d
        const int n = row0 + row;
        float rr[32];
        const float* zr = z + (size_t)n * DD + d0;
        #pragma unroll
        for (int q = 0; q < 8; ++q) {
            const float4 v = *(const float4*)(zr + q * 4);
            rr[q * 4 + 0] = v.x; rr[q * 4 + 1] = v.y;
            rr[q * 4 + 2] = v.z; rr[q * 4 + 3] = v.w;
        }
        for (int h = 0; h < c; ++h) {
            const int ih = (int)out_idx[(size_t)n * NCB + h];
            const float* w = cb + ((size_t)h * KK + ih) * DD + d0;
            #pragma unroll
            for (int q = 0; q < 8; ++q) {
                const float4 v = *(const float4*)(w + q * 4);
                rr[q * 4 + 0] -= v.x; rr[q * 4 + 1] -= v.y;
                rr[q * 4 + 2] -= v.z; rr[q * 4 + 3] -= v.w;
            }
        }
        double ssq = 0.0;
        #pragma unroll
        for (int q = 0; q < 8; ++q) {
            *(float4*)&r_s[row][d0 + q * 4] =
                make_float4(rr[q*4], rr[q*4+1], rr[q*4+2], rr[q*4+3]);
            #pragma unroll
            for (int j = 0; j < 4; ++j) {
                const double v = (double)rr[q * 4 + j];
                ssq += v * v;
            }
        }
        if (c > 0) {
            for (int off = 32; off; off >>= 1) ssq += __shfl_down(ssq, off);
            if (lane == 0) lred[wv] = ssq;
        }
    }
    __syncthreads();
    if (c > 0 && tid == 0) {
        double s = 0.0;
        #pragma unroll
        for (int w = 0; w < 8; ++w) s += lred[w];
        atomicAdd(&loss[c - 1], s);
    }

    // ---- rss: numpy pairwise (pw128 + pw128), one row per lane of wave 0 ----
    if (tid < 64) {
        float res[2];
        #pragma unroll
        for (int half = 0; half < 2; ++half) {
            const int base = half * 128;
            float acc[8];
            #pragma unroll
            for (int j = 0; j < 8; ++j) {
                const float x = r_s[tid][base + j];
                acc[j] = fp32_barrier(x * x);
            }
            #pragma unroll
            for (int i = 8; i < 128; i += 8)
                #pragma unroll
                for (int j = 0; j < 8; ++j) {
                    const float x = r_s[tid][base + i + j];
                    acc[j] += fp32_barrier(x * x);
                }
            res[half] = ((acc[0] + acc[1]) + (acc[2] + acc[3])) +
                        ((acc[4] + acc[5]) + (acc[6] + acc[7]));
        }
        rss_s[tid] = res[0] + res[1];
    }

    float acc[16][8];
    #pragma unroll
    for (int rr = 0; rr < 16; ++rr)
        #pragma unroll
        for (int j = 0; j < 8; ++j) acc[rr][j] = 0.f;

    // ---- prologue: DMA chunk 0 into buffer 0 (4 GLL per thread) ----
    {
        const float* g0 = WTc;                 // chunk 0 = first 8192 floats
        #pragma unroll
        for (int q = 0; q < 4; ++q) {
            const int gbase = wv * 64 + 512 * q;          // wave-uniform granule
            gll16(g0 + (size_t)(gbase + lane) * 4, &W_s[0][gbase * 4]);
        }
    }
    __syncthreads();   // compiler drains vmcnt(0) before s_barrier

    const int klane = khalf * 512 + lane;      // base k for this lane

    #pragma unroll 1
    for (int ch = 0; ch < NCHUNK; ++ch) {
        // issue next chunk's DMA into the other buffer (zero registers held)
        if (ch + 1 < NCHUNK) {
            const float* gn = WTc + (size_t)(ch + 1) * CH * KK;
            float* lb = &W_s[(ch + 1) & 1][0];
            #pragma unroll
            for (int q = 0; q < 4; ++q) {
                const int gbase = wv * 64 + 512 * q;
                gll16(gn + (size_t)(gbase + lane) * 4, &lb[gbase * 4]);
            }
        }

        const float* Wb = &W_s[ch & 1][0];
        const int dbase = ch * CH;
        #pragma unroll
        for (int w2 = 0; w2 < CH / 2; ++w2) {
            const int dl = w2 * 2;
            float wv0[8], wv1[8];
            #pragma unroll
            for (int j = 0; j < 8; ++j) {
                wv0[j] = Wb[dl * KK + j * 64 + klane];
                wv1[j] = Wb[(dl + 1) * KK + j * 64 + klane];
            }
            #pragma unroll
            for (int rr = 0; rr < 16; ++rr) {
                const float2 rv = *(const float2*)&r_s[rowbase + rr][dbase + dl];
                #pragma unroll
                for (int j = 0; j < 8; ++j) {
                    float a = acc[rr][j];
                    a = __builtin_fmaf(rv.x, wv0[j], a);
                    a = __builtin_fmaf(rv.y, wv1[j], a);
                    acc[rr][j] = a;
                }
            }
        }
        __syncthreads();   // drains this wave's GLLs (vmcnt 0) + syncs buffers
    }

    // ---- scores + first-min argmin (wss loaded only now) ----
    float wssv[8];
    #pragma unroll
    for (int j = 0; j < 8; ++j) wssv[j] = wss[cK + khalf * 512 + j * 64 + lane];

    #pragma unroll
    for (int rr = 0; rr < 16; ++rr) {
        const float rs = rss_s[rowbase + rr];
        unsigned long long best = 0xFFFFFFFFFFFFFFFFULL;
        #pragma unroll
        for (int j = 0; j < 8; ++j) {
            const int kk = khalf * 512 + j * 64 + lane;
            const float sc = (rs - 2.0f * acc[rr][j]) + wssv[j];
            unsigned u = __float_as_uint(sc);
            u = ((int)u < 0) ? ~u : (u | 0x80000000u);
            const unsigned long long e = ((unsigned long long)u << 32) | (unsigned)kk;
            if (e < best) best = e;
        }
        #pragma unroll
        for (int off = 1; off < 64; off <<= 1) {
            const unsigned long long o = __shfl_xor(best, off);
            if (o < best) best = o;
        }
        if (lane == 0) arena[rowbase + rr][khalf] = best;
    }
    __syncthreads();
    if (tid < ROWS) {
        unsigned long long m = arena[tid][0];
        if (arena[tid][1] < m) m = arena[tid][1];
        out_idx[(size_t)(row0 + tid) * NCB + c] = (float)(int)(m & 0xFFFFFFFFULL);
    }
}

// ================= fallback path: exact R8 kernel (no workspace for WT) ====
#define WRL 17
__launch_bounds__(512, 1)
__global__ void step_kernel_f(const float* __restrict__ z, const float* __restrict__ cb,
                              float* __restrict__ out_idx, const float* __restrict__ wss,
                              double* __restrict__ loss, int c)
{
    __shared__ float r_s[ROWS][260];
    __shared__ float W_s[KK * WRL];
    __shared__ float rss_s[ROWS];
    __shared__ unsigned long long arena[ROWS][2];
    __shared__ double lred[8];

    const int tid = threadIdx.x;
    const int lane = tid & 63;
    const int wv = tid >> 6;
    const int rowbase = (wv & 3) * 16;
    const int khalf = wv >> 2;
    const int row0 = blockIdx.x * ROWS;
    const size_t cK = (size_t)c * KK;
    const float* Wc = cb + cK * DD;

    {
        const int row = tid >> 3;
        const int d0 = (tid & 7) * 32;
        const int n = row0 + row;
        float rr[32];
        const float* zr = z + (size_t)n * DD + d0;
        #pragma unroll
        for (int q = 0; q < 8; ++q) {
            const float4 v = *(const float4*)(zr + q * 4);
            rr[q * 4 + 0] = v.x; rr[q * 4 + 1] = v.y;
            rr[q * 4 + 2] = v.z; rr[q * 4 + 3] = v.w;
        }
        for (int h = 0; h < c; ++h) {
            const int ih = (int)out_idx[(size_t)n * NCB + h];
            const float* w = cb + ((size_t)h * KK + ih) * DD + d0;
            #pragma unroll
            for (int q = 0; q < 8; ++q) {
                const float4 v = *(const float4*)(w + q * 4);
                rr[q * 4 + 0] -= v.x; rr[q * 4 + 1] -= v.y;
                rr[q * 4 + 2] -= v.z; rr[q * 4 + 3] -= v.w;
            }
        }
        double ssq = 0.0;
        #pragma unroll
        for (int q = 0; q < 8; ++q) {
            *(float4*)&r_s[row][d0 + q * 4] =
                make_float4(rr[q*4], rr[q*4+1], rr[q*4+2], rr[q*4+3]);
            #pragma unroll
            for (int j = 0; j < 4; ++j) {
                const double v = (double)rr[q * 4 + j];
                ssq += v * v;
            }
        }
        if (c > 0) {
            for (int off = 32; off; off >>= 1) ssq += __shfl_down(ssq, off);
            if (lane == 0) lred[wv] = ssq;
        }
    }
    __syncthreads();
    if (c > 0 && tid == 0) {
        double s = 0.0;
        #pragma unroll
        for (int w = 0; w < 8; ++w) s += lred[w];
        atomicAdd(&loss[c - 1], s);
    }

    if (tid < 64) {
        float res[2];
        #pragma unroll
        for (int half = 0; half < 2; ++half) {
            const int base = half * 128;
            float acc[8];
            #pragma unroll
            for (int j = 0; j < 8; ++j) {
                const float x = r_s[tid][base + j];
                acc[j] = fp32_barrier(x * x);
            }
            #pragma unroll
            for (int i = 8; i < 128; i += 8)
                #pragma unroll
                for (int j = 0; j < 8; ++j) {
                    const float x = r_s[tid][base + i + j];
                    acc[j] += fp32_barrier(x * x);
                }
            res[half] = ((acc[0] + acc[1]) + (acc[2] + acc[3])) +
                        ((acc[4] + acc[5]) + (acc[6] + acc[7]));
        }
        rss_s[tid] = res[0] + res[1];
    }

    float acc[16][8];
    #pragma unroll
    for (int rr = 0; rr < 16; ++rr)
        #pragma unroll
        for (int j = 0; j < 8; ++j) acc[rr][j] = 0.f;

    const int kbase_lane = (khalf * 512 + lane) * WRL;

    #pragma unroll 1
    for (int ch = 0; ch < 16; ++ch) {
        __syncthreads();
        {
            const float* src = Wc + ch * 16;
            #pragma unroll
            for (int q = 0; q < 8; ++q) {
                const int f = tid + 512 * q;
                const int k = f >> 2, quad = f & 3;
                const float4 v = *(const float4*)(src + (size_t)k * DD + quad * 4);
                float* dst = &W_s[k * WRL + quad * 4];
                dst[0] = v.x; dst[1] = v.y; dst[2] = v.z; dst[3] = v.w;
            }
        }
        __syncthreads();

        const int dbase = ch * 16;
        #pragma unroll
        for (int w2 = 0; w2 < 8; ++w2) {
            const int dl = w2 * 2;
            float wv0[8], wv1[8];
            #pragma unroll
            for (int j = 0; j < 8; ++j) {
                const int b = kbase_lane + j * 64 * WRL + dl;
                wv0[j] = W_s[b];
                wv1[j] = W_s[b + 1];
            }
            #pragma unroll
            for (int rr = 0; rr < 16; ++rr) {
                const float2 rv = *(const float2*)&r_s[rowbase + rr][dbase + dl];
                #pragma unroll
                for (int j = 0; j < 8; ++j) {
                    float a = acc[rr][j];
                    a = __builtin_fmaf(rv.x, wv0[j], a);
                    a = __builtin_fmaf(rv.y, wv1[j], a);
                    acc[rr][j] = a;
                }
            }
        }
    }

    float wssv[8];
    #pragma unroll
    for (int j = 0; j < 8; ++j) wssv[j] = wss[cK + khalf * 512 + j * 64 + lane];

    #pragma unroll
    for (int rr = 0; rr < 16; ++rr) {
        const float rs = rss_s[rowbase + rr];
        unsigned long long best = 0xFFFFFFFFFFFFFFFFULL;
        #pragma unroll
        for (int j = 0; j < 8; ++j) {
            const int kk = khalf * 512 + j * 64 + lane;
            const float sc = (rs - 2.0f * acc[rr][j]) + wssv[j];
            unsigned u = __float_as_uint(sc);
            u = ((int)u < 0) ? ~u : (u | 0x80000000u);
            const unsigned long long e = ((unsigned long long)u << 32) | (unsigned)kk;
            if (e < best) best = e;
        }
        #pragma unroll
        for (int off = 1; off < 64; off <<= 1) {
            const unsigned long long o = __shfl_xor(best, off);
            if (o < best) best = o;
        }
        if (lane == 0) arena[rowbase + rr][khalf] = best;
    }
    __syncthreads();
    if (tid < ROWS) {
        unsigned long long m = arena[tid][0];
        if (arena[tid][1] < m) m = arena[tid][1];
        out_idx[(size_t)(row0 + tid) * NCB + c] = (float)(int)(m & 0xFFFFFFFFULL);
    }
}

// ---- quantized (fp32 sequential accumulation, reference order) + last loss ----
__launch_bounds__(1024)
__global__ void final_kernel(const float* __restrict__ z, const float* __restrict__ cb,
                             const float* __restrict__ out_idx, float* __restrict__ outq,
                             double* __restrict__ lpart)
{
    __shared__ double lred[16];
    const int lane = threadIdx.x & 63;
    const int w = threadIdx.x >> 6;
    const int n = blockIdx.x * 16 + w;
    const int d = lane * 4;

    int idx[NCB];
    #pragma unroll
    for (int j = 0; j < NCB; ++j) idx[j] = (int)out_idx[(size_t)n * NCB + j];
    float4 wv[NCB];
    #pragma unroll
    for (int j = 0; j < NCB; ++j)
        wv[j] = *(const float4*)(cb + ((size_t)j * KK + idx[j]) * DD + d);

    float4 rv = *(const float4*)(z + (size_t)n * DD + d);
    float q0 = 0.f, q1 = 0.f, q2 = 0.f, q3 = 0.f;
    #pragma unroll
    for (int j = 0; j < NCB; ++j) {
        q0 += wv[j].x; q1 += wv[j].y; q2 += wv[j].z; q3 += wv[j].w;
        rv.x -= wv[j].x; rv.y -= wv[j].y; rv.z -= wv[j].z; rv.w -= wv[j].w;
    }
    *(float4*)(outq + (size_t)n * DD + d) = make_float4(q0, q1, q2, q3);

    double ss = (double)rv.x * rv.x + (double)rv.y * rv.y +
                (double)rv.z * rv.z + (double)rv.w * rv.w;
    for (int off = 32; off; off >>= 1) ss += __shfl_down(ss, off);
    if (lane == 0) lred[w] = ss;
    __syncthreads();
    if (threadIdx.x == 0) {
        double s = 0.0;
        #pragma unroll
        for (int i = 0; i < 16; ++i) s += lred[i];
        atomicAdd(&lpart[blockIdx.x & 63], s);
    }
}

__global__ void loss_write_kernel(const double* __restrict__ loss,
                                  const double* __restrict__ lpart,
                                  float* __restrict__ out_loss) {
    double s = 0.0;
    for (int i = 0; i < NCB; ++i) s += loss[i];
    for (int i = 0; i < 64; ++i) s += lpart[i];
    *out_loss = (float)(s / 16777216.0);
}

extern "C" void kernel_launch(void* const* d_in, const int* in_sizes, int n_in,
                              void* d_out, int out_size, void* d_ws, size_t ws_size,
                              hipStream_t stream)
{
    const float* z  = (const float*)d_in[0];
    const float* cb = (const float*)d_in[1];
    float* outq     = (float*)d_out;
    float* out_idx  = outq + QN;
    float* out_loss = outq + QN + IDXN;

    double* loss  = (double*)d_ws;                  // 64 B  (slots 0..6 used)
    double* lpart = (double*)((char*)d_ws + 64);    // 512 B (striped term 7)
    float*  wss   = (float*)((char*)d_ws + 1024);   // 32 KB
    float*  WT    = (float*)((char*)d_ws + 65536);  // 8 MB transposed codebooks

    const bool use_wt = ws_size >= (size_t)65536 + (size_t)NCB * DD * KK * 4;

    hipMemsetAsync(d_ws, 0, 576, stream);
    wss_kernel<<<dim3((NCB * KK + 255) / 256), dim3(256), 0, stream>>>(cb, wss);
    if (use_wt) {
        wt_kernel<<<dim3(512), dim3(256), 0, stream>>>(cb, WT);
        for (int c = 0; c < NCB; ++c)
            step_kernel_t<<<dim3(NROWS / ROWS), dim3(512), 0, stream>>>(z, cb, WT, out_idx, wss, loss, c);
    } else {
        for (int c = 0; c < NCB; ++c)
            step_kernel_f<<<dim3(NROWS / ROWS), dim3(512), 0, stream>>>(z, cb, out_idx, wss, loss, c);
    }
    final_kernel<<<dim3(NROWS / 16), dim3(1024), 0, stream>>>(z, cb, out_idx, outq, lpart);
    loss_write_kernel<<<1, 1, 0, stream>>>(loss, lpart, out_loss);
}

// Round 13
// 3714.034 us; speedup vs baseline: 8.8706x; 1.2368x over previous
//
#include <hip/hip_runtime.h>

#define NROWS 65536
#define DD 256
#define KK 1024
#define NCB 8
#define QN 16777216
#define IDXN 524288
#define MARGIN 4e-3f

typedef __attribute__((ext_vector_type(8))) short bf16x8;
typedef __attribute__((ext_vector_type(4))) float f32x4;
typedef unsigned long long u64;

// Defeat -ffp-contract=fast where a separately-rounded product is required.
__device__ __forceinline__ float fp32_barrier(float x) {
    asm volatile("" : "+v"(x));
    return x;
}

__device__ __forceinline__ unsigned short f2bf(float x) {   // RNE fp32->bf16
    union { float f; unsigned u; } v; v.f = x;
    return (unsigned short)((v.u + 0x7fffu + ((v.u >> 16) & 1u)) >> 16);
}

__device__ __forceinline__ u64 enc_sc(float sc, int k) {
    unsigned u = __float_as_uint(sc);
    u = ((int)u < 0) ? ~u : (u | 0x80000000u);
    return ((u64)u << 32) | (unsigned)k;
}

// ---- numpy pairwise ||w||^2 per codeword (bitwise np.sum semantics) ----
__global__ void wss_kernel(const float* __restrict__ cb, float* __restrict__ wss) {
    const int g = blockIdx.x * blockDim.x + threadIdx.x;
    if (g >= NCB * KK) return;
    const float* w = cb + (size_t)g * DD;
    float res0 = 0.f, res1 = 0.f;
    #pragma unroll
    for (int half = 0; half < 2; ++half) {
        const float* p = w + half * 128;
        float acc[8];
        #pragma unroll
        for (int j = 0; j < 8; ++j) acc[j] = fp32_barrier(p[j] * p[j]);
        #pragma unroll
        for (int i = 8; i < 128; i += 8)
            #pragma unroll
            for (int j = 0; j < 8; ++j) acc[j] += fp32_barrier(p[i + j] * p[i + j]);
        const float t = ((acc[0] + acc[1]) + (acc[2] + acc[3])) +
                        ((acc[4] + acc[5]) + (acc[6] + acc[7]));
        if (half == 0) res0 = t; else res1 = t;
    }
    wss[g] = res0 + res1;
}

// ---- codebooks -> bf16 (RNE), same k-major layout ----
__global__ void wbf_kernel(const float* __restrict__ cb, unsigned* __restrict__ Wbf) {
    const int base = (blockIdx.x * 256 + threadIdx.x) * 4;
    #pragma unroll
    for (int j = 0; j < 4; ++j) {
        const int g = base + j;                       // u32 index, 2 bf16 each
        const unsigned lo = f2bf(cb[2 * g]);
        const unsigned hi = f2bf(cb[2 * g + 1]);
        Wbf[g] = lo | (hi << 16);
    }
}

// ---- runtime MFMA A/B-layout self-verification (C/D layout is HW-verified) ----
__global__ void probe_kernel(float* __restrict__ flagp) {
    const int l = threadIdx.x;
    const int m = l & 15, kb = (l >> 4) * 8;
    bf16x8 a1, a2, b1, b2;
    #pragma unroll
    for (int e = 0; e < 8; ++e) {
        a1[e] = (short)f2bf((float)m);
        a2[e] = (short)f2bf((float)(kb + e));
        b1[e] = (short)f2bf((kb + e == 5) ? 1.f : 0.f);
        b2[e] = (short)f2bf((kb + e == 5 && m == 3) ? 1.f : 0.f);
    }
    f32x4 z = {0.f, 0.f, 0.f, 0.f};
    f32x4 d1 = __builtin_amdgcn_mfma_f32_16x16x32_bf16(a1, b1, z, 0, 0, 0);
    f32x4 d2 = __builtin_amdgcn_mfma_f32_16x16x32_bf16(a2, b2, z, 0, 0, 0);
    bool ok = true;
    const int col = l & 15, rbase = (l >> 4) * 4;
    #pragma unroll
    for (int reg = 0; reg < 4; ++reg) {
        ok = ok && (d1[reg] == (float)(rbase + reg));            // A m-map vs D row
        ok = ok && (d2[reg] == ((col == 3) ? 5.f : 0.f));        // k-align + B n-map
    }
    const int good = __all(ok ? 1 : 0);
    if (l == 0) *flagp = good ? 3.0f : 1.0f;
}

// ---- one RVQ step: MFMA pruning + exact fp32-chain rescore ----
// Final indices bitwise-identical to reference fp32 semantics: candidate set
// provably contains the true argmin (margin 4e-3 vs ~6e-4 bf16 error bound);
// candidates rescored with the exact fp32 fma chain (d=0..255 ascending,
// single accumulator) + (rss-2a)+wss + first-min encode. nc==0 (defensive)
// and nc>8 rows get an exact full scan.
__launch_bounds__(512, 1)
__global__ void step_kernel(const float* __restrict__ z, const float* __restrict__ cb,
                            const unsigned short* __restrict__ Wbf,
                            float* __restrict__ out_idx, const float* __restrict__ wss,
                            double* __restrict__ loss, const float* __restrict__ flagp,
                            int c)
{
    __shared__ float r_s[64][260];            // fp32 residual (exact trajectory)
    __shared__ unsigned short rb_s[64][264];  // bf16 residual: 256 data + 8 pad shorts
    __shared__ float rss_s[64];
    __shared__ float rminp[64][4];
    __shared__ float rmin_s[64];
    __shared__ int cand[64][8];
    __shared__ u64 encl[64][8];
    __shared__ int cnt[64];
    __shared__ int ovfq[64];
    __shared__ int novf;
    __shared__ double lred[8];
    __shared__ u64 warena[8];

    const int tid = threadIdx.x;
    const int lane = tid & 63;
    const int wv = tid >> 6;
    const int row0 = blockIdx.x * 64;
    const size_t cK = (size_t)c * KK;

    if (tid < 64) cnt[tid] = 0;
    if (tid == 0) novf = 0;

    // ---- stage residual: fp32 reference trajectory + bf16 copy ----
    {
        const int row = tid >> 3;              // 0..63
        const int d0 = (tid & 7) * 32;
        const int n = row0 + row;
        float rr[32];
        const float* zr = z + (size_t)n * DD + d0;
        #pragma unroll
        for (int q = 0; q < 8; ++q) {
            const float4 v = *(const float4*)(zr + q * 4);
            rr[q * 4 + 0] = v.x; rr[q * 4 + 1] = v.y;
            rr[q * 4 + 2] = v.z; rr[q * 4 + 3] = v.w;
        }
        for (int h = 0; h < c; ++h) {
            const int ih = (int)out_idx[(size_t)n * NCB + h];
            const float* w = cb + ((size_t)h * KK + ih) * DD + d0;
            #pragma unroll
            for (int q = 0; q < 8; ++q) {
                const float4 v = *(const float4*)(w + q * 4);
                rr[q * 4 + 0] -= v.x; rr[q * 4 + 1] -= v.y;
                rr[q * 4 + 2] -= v.z; rr[q * 4 + 3] -= v.w;
            }
        }
        double ssq = 0.0;
        #pragma unroll
        for (int q = 0; q < 8; ++q) {
            *(float4*)&r_s[row][d0 + q * 4] =
                make_float4(rr[q*4], rr[q*4+1], rr[q*4+2], rr[q*4+3]);
            #pragma unroll
            for (int j = 0; j < 4; ++j) {
                const double v = (double)rr[q * 4 + j];
                ssq += v * v;
            }
        }
        unsigned* rbrow = (unsigned*)&rb_s[row][0];   // row = 132 u32, writes 0..127
        #pragma unroll
        for (int j = 0; j < 16; ++j) {
            const unsigned lo = f2bf(rr[2 * j]);
            const unsigned hi = f2bf(rr[2 * j + 1]);
            rbrow[d0 / 2 + j] = lo | (hi << 16);
        }
        if (c > 0) {
            for (int off = 32; off; off >>= 1) ssq += __shfl_down(ssq, off);
            if (lane == 0) lred[wv] = ssq;
        }
    }
    __syncthreads();
    if (c > 0 && tid == 0) {
        double s = 0.0;
        #pragma unroll
        for (int w = 0; w < 8; ++w) s += lred[w];
        atomicAdd(&loss[c - 1], s);
    }

    // ---- rss: numpy pairwise (pw128 + pw128) ----
    if (tid < 64) {
        float res[2];
        #pragma unroll
        for (int half = 0; half < 2; ++half) {
            const int base = half * 128;
            float acc[8];
            #pragma unroll
            for (int j = 0; j < 8; ++j) {
                const float x = r_s[tid][base + j];
                acc[j] = fp32_barrier(x * x);
            }
            #pragma unroll
            for (int i = 8; i < 128; i += 8)
                #pragma unroll
                for (int j = 0; j < 8; ++j) {
                    const float x = r_s[tid][base + i + j];
                    acc[j] += fp32_barrier(x * x);
                }
            res[half] = ((acc[0] + acc[1]) + (acc[2] + acc[3])) +
                        ((acc[4] + acc[5]) + (acc[6] + acc[7]));
        }
        rss_s[tid] = res[0] + res[1];
    }
    __syncthreads();

    const int flag = (int)*flagp;   // uniform

    if (flag == 3) {
        // ======== MFMA path ========
        const int kq = wv & 3;                 // 256-k quarter
        const int rset = wv >> 2;              // 0/1 -> 32-row half
        const int mrow0 = rset * 32;
        const int colk = lane & 15, kg = lane >> 4;

        float rssA[4], rssB[4], rmA[4], rmB[4];
        #pragma unroll
        for (int reg = 0; reg < 4; ++reg) {
            rssA[reg] = rss_s[mrow0 + kg * 4 + reg];
            rssB[reg] = rss_s[mrow0 + 16 + kg * 4 + reg];
            rmA[reg] = INFINITY; rmB[reg] = INFINITY;
        }
        const unsigned short* Wq = Wbf + (cK + (size_t)kq * 256) * DD;

        // phase A: scores + running per-lane row-min
        for (int s = 0; s < 16; ++s) {
            f32x4 acc0 = {0.f,0.f,0.f,0.f}, acc1 = {0.f,0.f,0.f,0.f};
            const unsigned short* wk = Wq + (size_t)(s * 16 + colk) * DD + kg * 8;
            #pragma unroll
            for (int t = 0; t < 8; ++t) {
                const bf16x8 bf = *(const bf16x8*)(wk + t * 32);
                const bf16x8 a0 = *(const bf16x8*)&rb_s[mrow0 + colk][t * 32 + kg * 8];
                const bf16x8 a1 = *(const bf16x8*)&rb_s[mrow0 + 16 + colk][t * 32 + kg * 8];
                acc0 = __builtin_amdgcn_mfma_f32_16x16x32_bf16(a0, bf, acc0, 0, 0, 0);
                acc1 = __builtin_amdgcn_mfma_f32_16x16x32_bf16(a1, bf, acc1, 0, 0, 0);
            }
            const float ws = wss[cK + kq * 256 + s * 16 + colk];
            #pragma unroll
            for (int reg = 0; reg < 4; ++reg) {
                const float sA = __builtin_fmaf(-2.f, acc0[reg], rssA[reg]) + ws;
                const float sB = __builtin_fmaf(-2.f, acc1[reg], rssB[reg]) + ws;
                rmA[reg] = fminf(rmA[reg], sA);
                rmB[reg] = fminf(rmB[reg], sB);
            }
        }
        #pragma unroll
        for (int off = 1; off < 16; off <<= 1) {
            #pragma unroll
            for (int reg = 0; reg < 4; ++reg) {
                rmA[reg] = fminf(rmA[reg], __shfl_xor(rmA[reg], off));
                rmB[reg] = fminf(rmB[reg], __shfl_xor(rmB[reg], off));
            }
        }
        if (colk == 0) {
            #pragma unroll
            for (int reg = 0; reg < 4; ++reg) {
                rminp[mrow0 + kg * 4 + reg][kq] = rmA[reg];
                rminp[mrow0 + 16 + kg * 4 + reg][kq] = rmB[reg];
            }
        }
        __syncthreads();
        if (tid < 64) {
            float m = rminp[tid][0];
            m = fminf(m, rminp[tid][1]);
            m = fminf(m, rminp[tid][2]);
            m = fminf(m, rminp[tid][3]);
            rmin_s[tid] = m;
        }
        __syncthreads();

        // phase B: recompute + candidate extraction
        float thA[4], thB[4];
        #pragma unroll
        for (int reg = 0; reg < 4; ++reg) {
            thA[reg] = rmin_s[mrow0 + kg * 4 + reg] + MARGIN;
            thB[reg] = rmin_s[mrow0 + 16 + kg * 4 + reg] + MARGIN;
        }
        for (int s = 0; s < 16; ++s) {
            f32x4 acc0 = {0.f,0.f,0.f,0.f}, acc1 = {0.f,0.f,0.f,0.f};
            const unsigned short* wk = Wq + (size_t)(s * 16 + colk) * DD + kg * 8;
            #pragma unroll
            for (int t = 0; t < 8; ++t) {
                const bf16x8 bf = *(const bf16x8*)(wk + t * 32);
                const bf16x8 a0 = *(const bf16x8*)&rb_s[mrow0 + colk][t * 32 + kg * 8];
                const bf16x8 a1 = *(const bf16x8*)&rb_s[mrow0 + 16 + colk][t * 32 + kg * 8];
                acc0 = __builtin_amdgcn_mfma_f32_16x16x32_bf16(a0, bf, acc0, 0, 0, 0);
                acc1 = __builtin_amdgcn_mfma_f32_16x16x32_bf16(a1, bf, acc1, 0, 0, 0);
            }
            const int kkk = kq * 256 + s * 16 + colk;
            const float ws = wss[cK + kkk];
            #pragma unroll
            for (int reg = 0; reg < 4; ++reg) {
                const float sA = __builtin_fmaf(-2.f, acc0[reg], rssA[reg]) + ws;
                if (sA <= thA[reg]) {
                    const int rrow = mrow0 + kg * 4 + reg;
                    const int ix = atomicAdd(&cnt[rrow], 1);
                    if (ix < 8) cand[rrow][ix] = kkk;
                }
                const float sB = __builtin_fmaf(-2.f, acc1[reg], rssB[reg]) + ws;
                if (sB <= thB[reg]) {
                    const int rrow = mrow0 + 16 + kg * 4 + reg;
                    const int ix = atomicAdd(&cnt[rrow], 1);
                    if (ix < 8) cand[rrow][ix] = kkk;
                }
            }
        }
        __syncthreads();

        // ---- exact fp32-chain rescore of candidates ----
        {
            const int rrow = tid >> 3, slot = tid & 7;
            const int nc = cnt[rrow];
            if (slot < (nc > 8 ? 8 : nc)) {
                const int k = cand[rrow][slot];
                const float* wr = cb + (cK + k) * DD;
                float a = 0.f;
                for (int q = 0; q < 64; ++q) {
                    const float4 w4 = *(const float4*)(wr + q * 4);
                    a = __builtin_fmaf(r_s[rrow][q * 4 + 0], w4.x, a);
                    a = __builtin_fmaf(r_s[rrow][q * 4 + 1], w4.y, a);
                    a = __builtin_fmaf(r_s[rrow][q * 4 + 2], w4.z, a);
                    a = __builtin_fmaf(r_s[rrow][q * 4 + 3], w4.w, a);
                }
                const float sc = (rss_s[rrow] - 2.0f * a) + wss[cK + k];
                encl[rrow][slot] = enc_sc(sc, k);
            }
        }
        __syncthreads();
        if (tid < 64) {
            const int nc = cnt[tid];
            if (nc > 8 || nc == 0) {           // nc==0: defensive -> exact scan
                const int ix = atomicAdd(&novf, 1);
                ovfq[ix] = tid;
            } else {
                u64 m = 0xFFFFFFFFFFFFFFFFULL;
                for (int j = 0; j < nc; ++j)
                    if (encl[tid][j] < m) m = encl[tid][j];
                out_idx[(size_t)(row0 + tid) * NCB + c] = (float)(int)(m & 0xFFFFFFFFULL);
            }
        }
        __syncthreads();
        const int nq = novf;
        for (int qi = 0; qi < nq; ++qi) {    // rare: full exact scan of a row
            const int orow = ovfq[qi];
            const float rs = rss_s[orow];
            u64 best = 0xFFFFFFFFFFFFFFFFULL;
            for (int k = tid; k < KK; k += 512) {
                const float* wr = cb + (cK + k) * DD;
                float a = 0.f;
                for (int q = 0; q < 64; ++q) {
                    const float4 w4 = *(const float4*)(wr + q * 4);
                    a = __builtin_fmaf(r_s[orow][q * 4 + 0], w4.x, a);
                    a = __builtin_fmaf(r_s[orow][q * 4 + 1], w4.y, a);
                    a = __builtin_fmaf(r_s[orow][q * 4 + 2], w4.z, a);
                    a = __builtin_fmaf(r_s[orow][q * 4 + 3], w4.w, a);
                }
                const u64 e = enc_sc((rs - 2.0f * a) + wss[cK + k], k);
                if (e < best) best = e;
            }
            #pragma unroll
            for (int off = 1; off < 64; off <<= 1) {
                const u64 o = __shfl_xor(best, off);
                if (o < best) best = o;
            }
            if (lane == 0) warena[wv] = best;
            __syncthreads();
            if (tid == 0) {
                u64 m = warena[0];
                #pragma unroll
                for (int w = 1; w < 8; ++w) if (warena[w] < m) m = warena[w];
                out_idx[(size_t)(row0 + orow) * NCB + c] = (float)(int)(m & 0xFFFFFFFFULL);
            }
            __syncthreads();
        }
    } else {
        // ======== VALU fallback (layout probe failed) ========
        const int frow = tid >> 3, band = tid & 7;
        const float frss = rss_s[frow];
        u64 fb = 0xFFFFFFFFFFFFFFFFULL;
        const float* cbc = cb + cK * DD;
        for (int k = band * 128; k < band * 128 + 128; ++k) {
            const float* wr = cbc + (size_t)k * DD;
            float a = 0.f;
            for (int q = 0; q < 64; ++q) {
                const float4 w4 = *(const float4*)(wr + q * 4);
                a = __builtin_fmaf(r_s[frow][q * 4 + 0], w4.x, a);
                a = __builtin_fmaf(r_s[frow][q * 4 + 1], w4.y, a);
                a = __builtin_fmaf(r_s[frow][q * 4 + 2], w4.z, a);
                a = __builtin_fmaf(r_s[frow][q * 4 + 3], w4.w, a);
            }
            const u64 e = enc_sc((frss - 2.0f * a) + wss[cK + k], k);
            if (e < fb) fb = e;
        }
        encl[frow][band] = fb;
        __syncthreads();
        if (tid < 64) {
            u64 m = encl[tid][0];
            #pragma unroll
            for (int j = 1; j < 8; ++j) if (encl[tid][j] < m) m = encl[tid][j];
            out_idx[(size_t)(row0 + tid) * NCB + c] = (float)(int)(m & 0xFFFFFFFFULL);
        }
    }
}

// ---- quantized (fp32 sequential accumulation, reference order) + last loss ----
__launch_bounds__(1024)
__global__ void final_kernel(const float* __restrict__ z, const float* __restrict__ cb,
                             const float* __restrict__ out_idx, float* __restrict__ outq,
                             double* __restrict__ lpart)
{
    __shared__ double lred[16];
    const int lane = threadIdx.x & 63;
    const int w = threadIdx.x >> 6;
    const int n = blockIdx.x * 16 + w;
    const int d = lane * 4;

    int idx[NCB];
    #pragma unroll
    for (int j = 0; j < NCB; ++j) idx[j] = (int)out_idx[(size_t)n * NCB + j];
    float4 wv[NCB];
    #pragma unroll
    for (int j = 0; j < NCB; ++j)
        wv[j] = *(const float4*)(cb + ((size_t)j * KK + idx[j]) * DD + d);

    float4 rv = *(const float4*)(z + (size_t)n * DD + d);
    float q0 = 0.f, q1 = 0.f, q2 = 0.f, q3 = 0.f;
    #pragma unroll
    for (int j = 0; j < NCB; ++j) {
        q0 += wv[j].x; q1 += wv[j].y; q2 += wv[j].z; q3 += wv[j].w;
        rv.x -= wv[j].x; rv.y -= wv[j].y; rv.z -= wv[j].z; rv.w -= wv[j].w;
    }
    *(float4*)(outq + (size_t)n * DD + d) = make_float4(q0, q1, q2, q3);

    double ss = (double)rv.x * rv.x + (double)rv.y * rv.y +
                (double)rv.z * rv.z + (double)rv.w * rv.w;
    for (int off = 32; off; off >>= 1) ss += __shfl_down(ss, off);
    if (lane == 0) lred[w] = ss;
    __syncthreads();
    if (threadIdx.x == 0) {
        double s = 0.0;
        #pragma unroll
        for (int i = 0; i < 16; ++i) s += lred[i];
        atomicAdd(&lpart[blockIdx.x & 63], s);
    }
}

__global__ void loss_write_kernel(const double* __restrict__ loss,
                                  const double* __restrict__ lpart,
                                  float* __restrict__ out_loss) {
    double s = 0.0;
    for (int i = 0; i < NCB; ++i) s += loss[i];
    for (int i = 0; i < 64; ++i) s += lpart[i];
    *out_loss = (float)(s / 16777216.0);
}

extern "C" void kernel_launch(void* const* d_in, const int* in_sizes, int n_in,
                              void* d_out, int out_size, void* d_ws, size_t ws_size,
                              hipStream_t stream)
{
    const float* z  = (const float*)d_in[0];
    const float* cb = (const float*)d_in[1];
    float* outq     = (float*)d_out;
    float* out_idx  = outq + QN;
    float* out_loss = outq + QN + IDXN;

    double* loss  = (double*)d_ws;                          // 64 B (slots 0..6)
    double* lpart = (double*)((char*)d_ws + 64);            // 512 B
    float*  flagp = (float*)((char*)d_ws + 576);            // 4 B layout flag
    float*  wss   = (float*)((char*)d_ws + 1024);           // 32 KB
    unsigned short* Wbf = (unsigned short*)((char*)d_ws + 65536);  // 4 MB bf16 cb

    hipMemsetAsync(d_ws, 0, 1024, stream);
    probe_kernel<<<dim3(1), dim3(64), 0, stream>>>(flagp);
    wss_kernel<<<dim3((NCB * KK + 255) / 256), dim3(256), 0, stream>>>(cb, wss);
    wbf_kernel<<<dim3(1024), dim3(256), 0, stream>>>(cb, (unsigned*)Wbf);
    for (int c = 0; c < NCB; ++c) {
        step_kernel<<<dim3(NROWS / 64), dim3(512), 0, stream>>>(
            z, cb, Wbf, out_idx, wss, loss, flagp, c);
    }
    final_kernel<<<dim3(NROWS / 16), dim3(1024), 0, stream>>>(z, cb, out_idx, outq, lpart);
    loss_write_kernel<<<1, 1, 0, stream>>>(loss, lpart, out_loss);
}